// Round 1
// baseline (300.411 us; speedup 1.0000x reference)
//
#include <hip/hip_runtime.h>
#include <hip/hip_bf16.h>

// Problem constants (from reference): B=4, H=W=64 -> N=4096, C=64, d=8
#define BATCH 4
#define NTOK 4096
#define CCH 64
#define DQK 8

typedef short s16x8 __attribute__((ext_vector_type(8)));
typedef float f32x4 __attribute__((ext_vector_type(4)));

static __device__ __forceinline__ unsigned short f2bf(float f) {
    union { __hip_bfloat16 h; unsigned short u; } cv;
    cv.h = __float2bfloat16(f);
    return cv.u;
}

// ---------------------------------------------------------------------------
// Kernel A: projections. q = xWf+bf, k = xWg+bg (fp32, row-major [B][N][8]);
// v = xWh+bh stored TRANSPOSED bf16 as vT[B][C][N] so attention kernel can
// stage MFMA-B-operand tiles with contiguous 16B LDS reads.
// grid: B*64 blocks (64-row tiles), 256 threads.
// ---------------------------------------------------------------------------
__global__ __launch_bounds__(256) void proj_kernel(
    const float* __restrict__ xg,
    const float* __restrict__ Wf, const float* __restrict__ bf,
    const float* __restrict__ Wg, const float* __restrict__ bg,
    const float* __restrict__ Wh, const float* __restrict__ bh,
    float* __restrict__ qg, float* __restrict__ kg,
    unsigned short* __restrict__ vTg)
{
    __shared__ float xS[64 * 68];    // x tile, padded stride 68
    __shared__ float WhT[64 * 68];   // Wh transposed [c_out][c_in]
    __shared__ float WfS[64 * 8];
    __shared__ float WgS[64 * 8];

    const int t = threadIdx.x;
    const int blk = blockIdx.x;
    const int b = blk >> 6;
    const int n0 = (blk & 63) * 64;

    const float* xrow = xg + ((size_t)b * NTOK + n0) * CCH;
    // stage x tile: 64 rows x 64 ch = 1024 float4
    for (int f = t; f < 1024; f += 256) {
        int r = f >> 4, c4 = (f & 15) * 4;
        float4 v = *(const float4*)(xrow + r * 64 + c4);
        *(float4*)(xS + r * 68 + c4) = v;
    }
    // stage Wh transposed
    for (int e = t; e < 4096; e += 256) {
        int ci = e >> 6, co = e & 63;
        WhT[co * 68 + ci] = Wh[e];
    }
    // stage Wf / Wg
    if (t < 128) {
        int ci = t >> 1, d4 = (t & 1) * 4;
        *(float4*)(WfS + ci * 8 + d4) = *(const float4*)(Wf + ci * 8 + d4);
    } else {
        int f = t - 128;
        int ci = f >> 1, d4 = (f & 1) * 4;
        *(float4*)(WgS + ci * 8 + d4) = *(const float4*)(Wg + ci * 8 + d4);
    }
    __syncthreads();

    // ---- v: thread (c = t>>2, sub = t&3) computes vT[c][n0+sub*16 .. +15]
    {
        int c = t >> 2, sub = t & 3;
        float bias = bh[c];
        float acc[16];
        #pragma unroll
        for (int i = 0; i < 16; ++i) acc[i] = bias;
        for (int ci = 0; ci < 64; ci += 4) {
            float4 w4 = *(const float4*)(WhT + c * 68 + ci);
            #pragma unroll
            for (int i = 0; i < 16; ++i) {
                float4 x4 = *(const float4*)(xS + (sub * 16 + i) * 68 + ci);
                acc[i] += x4.x * w4.x + x4.y * w4.y + x4.z * w4.z + x4.w * w4.w;
            }
        }
        alignas(16) unsigned short us[16];
        #pragma unroll
        for (int i = 0; i < 16; ++i) us[i] = f2bf(acc[i]);
        uint4* dst = (uint4*)(vTg + ((size_t)b * CCH + c) * NTOK + n0 + sub * 16);
        dst[0] = *(uint4*)(us);
        dst[1] = *(uint4*)(us + 8);
    }

    // ---- q/k: thread (r = t>>2, dp = (t&3)*2) computes 2 q and 2 k channels
    {
        int r = t >> 2, dp = (t & 3) * 2;
        float q0 = bf[dp], q1 = bf[dp + 1];
        float k0 = bg[dp], k1 = bg[dp + 1];
        #pragma unroll 4
        for (int ci = 0; ci < 64; ++ci) {
            float xv = xS[r * 68 + ci];
            q0 += xv * WfS[ci * 8 + dp];
            q1 += xv * WfS[ci * 8 + dp + 1];
            k0 += xv * WgS[ci * 8 + dp];
            k1 += xv * WgS[ci * 8 + dp + 1];
        }
        size_t base = ((size_t)b * NTOK + n0 + r) * 8 + dp;
        *(float2*)(qg + base) = make_float2(q0, q1);
        *(float2*)(kg + base) = make_float2(k0, k1);
    }
}

// ---------------------------------------------------------------------------
// Kernel B: attention. grid = B * 128 blocks (32 query rows each), 256 thr.
// Phase 1: fp32 QK over all keys -> per-row sum of exp(s-20)  (constant shift
//          cancels exactly in softmax; data guarantees no overflow: row max
//          >= s[n][n] = |q|^2 >= 0, and s <= |q||k| << 80).
// Phase 2: per 64-key tile: recompute s, p = exp(s-20)/l -> bf16 LDS tile,
//          V tile staged bf16, PV via mfma_f32_16x16x32_bf16.
// ---------------------------------------------------------------------------
__global__ __launch_bounds__(256) void attn_kernel(
    const float* __restrict__ xg,
    const float* __restrict__ qg, const float* __restrict__ kg,
    const unsigned short* __restrict__ vTg,
    const float* __restrict__ gammaPtr,
    float* __restrict__ out)
{
    __shared__ float kS[64 * 8];
    __shared__ unsigned short PS[32 * 72];   // P tile bf16, padded stride 72
    __shared__ unsigned short VtS[64 * 72];  // V^T tile bf16 [ch][key]
    __shared__ float rlS[32];

    const int t = threadIdx.x;
    const int blk = blockIdx.x;
    const int b = blk >> 7;
    const int m0 = (blk & 127) * 32;

    const float* kbase = kg + (size_t)b * NTOK * 8;

    // each thread keeps its query row in registers (4 threads share a row)
    const int r = t >> 3, oc = t & 7;
    const float* qrow = qg + ((size_t)b * NTOK + m0 + r) * 8;
    const float4 qa = *(const float4*)qrow;
    const float4 qb = *(const float4*)(qrow + 4);

    // ---- phase 1: l[r] = sum_j exp(s-20)
    float lsum = 0.f;
    #pragma unroll 4
    for (int it = 0; it < 512; ++it) {
        int j = (it << 3) | oc;
        float4 ka = *(const float4*)(kbase + j * 8);
        float4 kb = *(const float4*)(kbase + j * 8 + 4);
        float s = qa.x * ka.x + qa.y * ka.y + qa.z * ka.z + qa.w * ka.w
                + qb.x * kb.x + qb.y * kb.y + qb.z * kb.z + qb.w * kb.w;
        lsum += __expf(s - 20.f);
    }
    lsum += __shfl_xor(lsum, 1);
    lsum += __shfl_xor(lsum, 2);
    lsum += __shfl_xor(lsum, 4);
    if (oc == 0) rlS[r] = 1.f / lsum;
    __syncthreads();
    const float rl = rlS[r];

    // MFMA lane mapping
    const int wv = t >> 6, lane = t & 63;
    const int mfr = wv & 1;          // which 16-row m-frag (0/1)
    const int nh = wv >> 1;          // which 32-channel half
    const int ml = lane & 15, quad = lane >> 4;
    f32x4 acc0 = {0.f, 0.f, 0.f, 0.f};
    f32x4 acc1 = {0.f, 0.f, 0.f, 0.f};

    const uint4* vtbase = (const uint4*)vTg + (size_t)b * CCH * 512; // 512 uint4 per row

    for (int jt = 0; jt < 64; ++jt) {
        __syncthreads();  // previous iter's PS/VtS/kS fully consumed
        // stage K tile (64 rows x 8 fp32)
        if (t < 128) {
            int row = t >> 1, half = (t & 1) * 4;
            *(float4*)(kS + row * 8 + half) =
                *(const float4*)(kbase + (size_t)(jt * 64 + row) * 8 + half);
        }
        // stage V^T tile (64 ch x 64 keys bf16): 2 x 16B chunks per thread
        {
            int e = t * 2;                   // even -> off8 in {0,2,4,6}
            int c = e >> 3, off8 = e & 7;
            const uint4* src = vtbase + (size_t)c * 512 + jt * 8 + off8;
            uint4 v0 = src[0];
            uint4 v1 = src[1];
            *(uint4*)(VtS + c * 72 + off8 * 8) = v0;
            *(uint4*)(VtS + c * 72 + (off8 + 1) * 8) = v1;
        }
        __syncthreads();
        // s + softmax-normalize -> PS (thread (r,oc) covers keys oc*8..oc*8+7)
        #pragma unroll
        for (int jj = 0; jj < 8; ++jj) {
            int j = oc * 8 + jj;
            const float* kr = kS + j * 8;
            float s = qa.x * kr[0] + qa.y * kr[1] + qa.z * kr[2] + qa.w * kr[3]
                    + qb.x * kr[4] + qb.y * kr[5] + qb.z * kr[6] + qb.w * kr[7];
            PS[r * 72 + j] = f2bf(__expf(s - 20.f) * rl);
        }
        __syncthreads();
        // MFMA: O += P(32x64) * V(64x64); wave covers 16 rows x 32 channels
        #pragma unroll
        for (int ks = 0; ks < 2; ++ks) {
            s16x8 a  = *(const s16x8*)(PS + (mfr * 16 + ml) * 72 + ks * 32 + quad * 8);
            s16x8 b0 = *(const s16x8*)(VtS + ((nh * 2 + 0) * 16 + ml) * 72 + ks * 32 + quad * 8);
            s16x8 b1 = *(const s16x8*)(VtS + ((nh * 2 + 1) * 16 + ml) * 72 + ks * 32 + quad * 8);
            acc0 = __builtin_amdgcn_mfma_f32_16x16x32_bf16(a, b0, acc0, 0, 0, 0);
            acc1 = __builtin_amdgcn_mfma_f32_16x16x32_bf16(a, b1, acc1, 0, 0, 0);
        }
    }

    // epilogue: out = gamma*o + x   (C-layout: col = lane&15, row = quad*4+reg)
    const float gamma = gammaPtr[0];
    #pragma unroll
    for (int reg = 0; reg < 4; ++reg) {
        int row = m0 + mfr * 16 + quad * 4 + reg;
        size_t base = ((size_t)b * NTOK + row) * CCH;
        int c0 = (nh * 2 + 0) * 16 + ml;
        int c1 = (nh * 2 + 1) * 16 + ml;
        out[base + c0] = gamma * acc0[reg] + xg[base + c0];
        out[base + c1] = gamma * acc1[reg] + xg[base + c1];
    }
}

extern "C" void kernel_launch(void* const* d_in, const int* in_sizes, int n_in,
                              void* d_out, int out_size, void* d_ws, size_t ws_size,
                              hipStream_t stream) {
    const float* x  = (const float*)d_in[0];
    const float* Wf = (const float*)d_in[1];
    const float* bf = (const float*)d_in[2];
    const float* Wg = (const float*)d_in[3];
    const float* bg = (const float*)d_in[4];
    const float* Wh = (const float*)d_in[5];
    const float* bh = (const float*)d_in[6];
    const float* gamma = (const float*)d_in[7];
    float* out = (float*)d_out;

    // workspace layout
    char* ws = (char*)d_ws;
    float* qg = (float*)ws;                               // B*N*8 fp32 = 512 KB
    float* kg = (float*)(ws + 524288);                    // B*N*8 fp32 = 512 KB
    unsigned short* vTg = (unsigned short*)(ws + 1048576); // B*C*N bf16 = 2 MB

    proj_kernel<<<BATCH * 64, 256, 0, stream>>>(x, Wf, bf, Wg, bg, Wh, bh,
                                                qg, kg, vTg);
    attn_kernel<<<BATCH * 128, 256, 0, stream>>>(x, qg, kg, vTg, gamma, out);
}

// Round 3
// 115.750 us; speedup vs baseline: 2.5953x; 2.5953x over previous
//
#include <hip/hip_runtime.h>
#include <hip/hip_bf16.h>

// Problem: B=4, H=W=64 -> N=4096 tokens, C=64, d=8
#define BATCH 4
#define NTOK 4096
#define CCH 64

typedef short s16x8 __attribute__((ext_vector_type(8)));
typedef float f32x4 __attribute__((ext_vector_type(4)));

static __device__ __forceinline__ unsigned short f2bf(float f) {
    union { __hip_bfloat16 h; unsigned short u; } cv;
    cv.h = __float2bfloat16(f);
    return cv.u;
}
// Dekker split: h = bf16(f) (RNE), returns exact residual f - h
static __device__ __forceinline__ float bf_split(float f, unsigned short& h) {
    h = f2bf(f);
    union { unsigned int u; float x; } c; c.u = ((unsigned)h) << 16;
    return f - c.x;
}

// ---------------------------------------------------------------------------
// Projections. Outputs:
//   Qpack[b][n][32] bf16 = [qh(8) | ql(8) | qh(8) | 0(8)]
//   Kpack[b][n][32] bf16 = [kh(8) | kh(8) | kl(8) | 0(8)]
//   (one 16x16x32 MFMA then gives s = qh*kh + ql*kh + qh*kl ~ fp32-accurate)
//   vT[b][c][n] bf16 (V transposed, B-operand friendly)
// grid: B*128 blocks (32-token tiles), 256 threads.
// ---------------------------------------------------------------------------
__global__ __launch_bounds__(256) void proj_kernel(
    const float* __restrict__ xg,
    const float* __restrict__ Wf, const float* __restrict__ bf_,
    const float* __restrict__ Wg, const float* __restrict__ bg,
    const float* __restrict__ Wh, const float* __restrict__ bh,
    unsigned short* __restrict__ Qp, unsigned short* __restrict__ Kp,
    unsigned short* __restrict__ vTg)
{
    __shared__ float xS[32 * 68];   // x tile [token][ci], pad 68
    __shared__ float WhT[64 * 68];  // Wh^T [c_out][c_in]
    __shared__ float WfT[8 * 68];   // Wf^T [j][ci]
    __shared__ float WgT[8 * 68];

    const int t = threadIdx.x;
    const int blk = blockIdx.x;
    const int b = blk >> 7;
    const int n0 = (blk & 127) * 32;

    const float* xrow = xg + ((size_t)b * NTOK + n0) * CCH;
    for (int f = t; f < 512; f += 256) {
        int r = f >> 4, c4 = (f & 15) * 4;
        *(float4*)(xS + r * 68 + c4) = *(const float4*)(xrow + r * 64 + c4);
    }
    for (int e = t; e < 4096; e += 256) {
        int ci = e >> 6, co = e & 63;
        WhT[co * 68 + ci] = Wh[e];
    }
    for (int e = t; e < 512; e += 256) {
        int ci = e >> 3, j = e & 7;
        WfT[j * 68 + ci] = Wf[e];
        WgT[j * 68 + ci] = Wg[e];
    }
    __syncthreads();

    // ---- v: thread (c = t>>2, sub = t&3) computes vT[c][n0+sub*8 .. +7]
    {
        int c = t >> 2, sub = t & 3;
        float bias = bh[c];
        float acc[8];
        #pragma unroll
        for (int i = 0; i < 8; ++i) acc[i] = bias;
        for (int ci = 0; ci < 64; ci += 4) {
            float4 w4 = *(const float4*)(WhT + c * 68 + ci);
            #pragma unroll
            for (int i = 0; i < 8; ++i) {
                float4 x4 = *(const float4*)(xS + (sub * 8 + i) * 68 + ci);
                acc[i] += x4.x * w4.x + x4.y * w4.y + x4.z * w4.z + x4.w * w4.w;
            }
        }
        alignas(16) unsigned short us[8];
        #pragma unroll
        for (int i = 0; i < 8; ++i) us[i] = f2bf(acc[i]);
        *(uint4*)(vTg + ((size_t)b * CCH + c) * NTOK + n0 + sub * 8) = *(uint4*)us;
    }

    // ---- q/k: thread (r = t>>3, j = t&7) computes one q and one k channel
    {
        int r = t >> 3, j = t & 7;
        float q = bf_[j], k = bg[j];
        for (int ci = 0; ci < 64; ci += 4) {
            float4 x4 = *(const float4*)(xS + r * 68 + ci);
            float4 wf4 = *(const float4*)(WfT + j * 68 + ci);
            float4 wg4 = *(const float4*)(WgT + j * 68 + ci);
            q += x4.x * wf4.x + x4.y * wf4.y + x4.z * wf4.z + x4.w * wf4.w;
            k += x4.x * wg4.x + x4.y * wg4.y + x4.z * wg4.z + x4.w * wg4.w;
        }
        unsigned short qh, kh;
        float qres = bf_split(q, qh);
        float kres = bf_split(k, kh);
        unsigned short ql = f2bf(qres), kl = f2bf(kres);
        size_t base = ((size_t)b * NTOK + n0 + r) * 32;
        Qp[base + j]      = qh;
        Qp[base + 8 + j]  = ql;
        Qp[base + 16 + j] = qh;
        Qp[base + 24 + j] = 0;
        Kp[base + j]      = kh;
        Kp[base + 8 + j]  = kh;
        Kp[base + 16 + j] = kl;
        Kp[base + 24 + j] = 0;
    }
}

// ---------------------------------------------------------------------------
// Attention, single pass. grid = B*128 blocks (32 query rows), 256 threads.
// Per 64-key tile:
//   S^T tiles via mfma(kfrag, qfrag)  (keys = rows -> packed b64 PS writes)
//   p = exp(s-20) -> bf16 PS[query][key] (double-buffered, 1 barrier/tile)
//   l += P*ones (MFMA row-sum), O += P*V (V^T frags direct from global)
// Epilogue: out = gamma * O/l + x.
// ---------------------------------------------------------------------------
__global__ __launch_bounds__(256) void attn_kernel(
    const float* __restrict__ xg,
    const unsigned short* __restrict__ Qp,
    const unsigned short* __restrict__ Kp,
    const unsigned short* __restrict__ vTg,
    const float* __restrict__ gammaPtr,
    float* __restrict__ out)
{
    __shared__ unsigned short PS[2][32 * 72];  // [query][key], stride 72 (144B)

    const int t = threadIdx.x;
    const int blk = blockIdx.x;
    const int b = blk >> 7;
    const int m0 = (blk & 127) * 32;
    const int w = t >> 6;            // wave: owns key-seg / channel-seg w*16..
    const int lane = t & 63;
    const int ml = lane & 15, quad = lane >> 4;

    const unsigned short* qpb = Qp + (size_t)b * NTOK * 32;
    const unsigned short* kpb = Kp + (size_t)b * NTOK * 32;
    const unsigned short* vtb = vTg + (size_t)b * CCH * NTOK;

    // Q B-operand frags (persist whole kernel): lane ml <-> query col
    const s16x8 qf0 = *(const s16x8*)(qpb + (size_t)(m0 + ml) * 32 + quad * 8);
    const s16x8 qf1 = *(const s16x8*)(qpb + (size_t)(m0 + 16 + ml) * 32 + quad * 8);

    s16x8 ones;
    #pragma unroll
    for (int i = 0; i < 8; ++i) ones[i] = (short)0x3F80;  // bf16 1.0

    f32x4 o0 = {0.f, 0.f, 0.f, 0.f}, o1 = {0.f, 0.f, 0.f, 0.f};
    f32x4 l0 = {0.f, 0.f, 0.f, 0.f}, l1 = {0.f, 0.f, 0.f, 0.f};
    const f32x4 zz = {0.f, 0.f, 0.f, 0.f};

    // prefetched frags for tile jt=0
    s16x8 kf  = *(const s16x8*)(kpb + (size_t)(w * 16 + ml) * 32 + quad * 8);
    s16x8 vf0 = *(const s16x8*)(vtb + (size_t)(w * 16 + ml) * NTOK + quad * 8);
    s16x8 vf1 = *(const s16x8*)(vtb + (size_t)(w * 16 + ml) * NTOK + 32 + quad * 8);

    for (int jt = 0; jt < 64; ++jt) {
        const int buf = jt & 1;
        const int jn = (jt + 1) & 63;  // wraps; tile 0 re-read, unused

        // S^T: rows = keys w*16+quad*4+reg, cols = queries (rf*16 + ml)
        f32x4 s0 = __builtin_amdgcn_mfma_f32_16x16x32_bf16(kf, qf0, zz, 0, 0, 0);
        f32x4 s1 = __builtin_amdgcn_mfma_f32_16x16x32_bf16(kf, qf1, zz, 0, 0, 0);

        // prefetch next K frag (independent of LDS)
        kf = *(const s16x8*)(kpb + (size_t)(jn * 64 + w * 16 + ml) * 32 + quad * 8);

        // p = exp(s - 20) -> bf16, packed b64 writes (4 consecutive keys)
        unsigned short h0[4], h1[4];
        #pragma unroll
        for (int rg = 0; rg < 4; ++rg) {
            h0[rg] = f2bf(__expf(s0[rg] - 20.f));
            h1[rg] = f2bf(__expf(s1[rg] - 20.f));
        }
        {
            uint2 d0 = { ((unsigned)h0[1] << 16) | h0[0],
                         ((unsigned)h0[3] << 16) | h0[2] };
            uint2 d1 = { ((unsigned)h1[1] << 16) | h1[0],
                         ((unsigned)h1[3] << 16) | h1[2] };
            *(uint2*)(&PS[buf][ml * 72 + w * 16 + quad * 4]) = d0;
            *(uint2*)(&PS[buf][(16 + ml) * 72 + w * 16 + quad * 4]) = d1;
        }
        __syncthreads();

        // A-frags: P[query m=ml][key k = ks*32 + quad*8 + j]
        const unsigned short* ps = PS[buf];
        s16x8 ap00 = *(const s16x8*)(ps + ml * 72 + quad * 8);
        s16x8 ap01 = *(const s16x8*)(ps + ml * 72 + 32 + quad * 8);
        s16x8 ap10 = *(const s16x8*)(ps + (16 + ml) * 72 + quad * 8);
        s16x8 ap11 = *(const s16x8*)(ps + (16 + ml) * 72 + 32 + quad * 8);

        // prefetch next V frags (channel = w*16+ml, keys jn*64 + ...)
        s16x8 nvf0 = *(const s16x8*)(vtb + (size_t)(w * 16 + ml) * NTOK + jn * 64 + quad * 8);
        s16x8 nvf1 = *(const s16x8*)(vtb + (size_t)(w * 16 + ml) * NTOK + jn * 64 + 32 + quad * 8);

        // l += P * ones  (row-sum; all cols identical, aligns with O rows)
        l0 = __builtin_amdgcn_mfma_f32_16x16x32_bf16(ap00, ones, l0, 0, 0, 0);
        l0 = __builtin_amdgcn_mfma_f32_16x16x32_bf16(ap01, ones, l0, 0, 0, 0);
        l1 = __builtin_amdgcn_mfma_f32_16x16x32_bf16(ap10, ones, l1, 0, 0, 0);
        l1 = __builtin_amdgcn_mfma_f32_16x16x32_bf16(ap11, ones, l1, 0, 0, 0);

        // O += P * V
        o0 = __builtin_amdgcn_mfma_f32_16x16x32_bf16(ap00, vf0, o0, 0, 0, 0);
        o0 = __builtin_amdgcn_mfma_f32_16x16x32_bf16(ap01, vf1, o0, 0, 0, 0);
        o1 = __builtin_amdgcn_mfma_f32_16x16x32_bf16(ap10, vf0, o1, 0, 0, 0);
        o1 = __builtin_amdgcn_mfma_f32_16x16x32_bf16(ap11, vf1, o1, 0, 0, 0);

        vf0 = nvf0; vf1 = nvf1;
    }

    // epilogue: out = gamma * O/l + x
    const float gamma = gammaPtr[0];
    #pragma unroll
    for (int rg = 0; rg < 4; ++rg) {
        int row0 = m0 + quad * 4 + rg;       // queries 0..15 tile (o0/l0)
        int row1 = row0 + 16;                // queries 16..31 tile (o1/l1)
        int col = w * 16 + ml;
        size_t i0 = ((size_t)b * NTOK + row0) * CCH + col;
        size_t i1 = ((size_t)b * NTOK + row1) * CCH + col;
        out[i0] = gamma * (o0[rg] / l0[rg]) + xg[i0];
        out[i1] = gamma * (o1[rg] / l1[rg]) + xg[i1];
    }
}

extern "C" void kernel_launch(void* const* d_in, const int* in_sizes, int n_in,
                              void* d_out, int out_size, void* d_ws, size_t ws_size,
                              hipStream_t stream) {
    const float* x  = (const float*)d_in[0];
    const float* Wf = (const float*)d_in[1];
    const float* bf = (const float*)d_in[2];
    const float* Wg = (const float*)d_in[3];
    const float* bg = (const float*)d_in[4];
    const float* Wh = (const float*)d_in[5];
    const float* bh = (const float*)d_in[6];
    const float* gamma = (const float*)d_in[7];
    float* out = (float*)d_out;

    // workspace: Qpack 1MB | Kpack 1MB | vT 2MB
    char* ws = (char*)d_ws;
    unsigned short* Qp  = (unsigned short*)ws;
    unsigned short* Kp  = (unsigned short*)(ws + (1u << 20));
    unsigned short* vTg = (unsigned short*)(ws + (2u << 20));

    proj_kernel<<<BATCH * 128, 256, 0, stream>>>(x, Wf, bf, Wg, bg, Wh, bh,
                                                 Qp, Kp, vTg);
    attn_kernel<<<BATCH * 128, 256, 0, stream>>>(x, Qp, Kp, vTg, gamma, out);
}

// Round 4
// 109.338 us; speedup vs baseline: 2.7475x; 1.0586x over previous
//
#include <hip/hip_runtime.h>
#include <hip/hip_bf16.h>

// Problem: B=4, H=W=64 -> N=4096 tokens, C=64, d=8
#define BATCH 4
#define NTOK 4096
#define CCH 64
#define KSPLIT 4
#define KPB (NTOK / KSPLIT)   // 1024 keys per attn block
#define NTILE (KPB / 64)      // 16 key tiles per attn block

typedef short s16x8 __attribute__((ext_vector_type(8)));
typedef float f32x4 __attribute__((ext_vector_type(4)));

static __device__ __forceinline__ unsigned short f2bf(float f) {
    union { __hip_bfloat16 h; unsigned short u; } cv;
    cv.h = __float2bfloat16(f);
    return cv.u;
}
static __device__ __forceinline__ float bf2f(unsigned short u) {
    union { unsigned int u; float f; } c; c.u = ((unsigned)u) << 16;
    return c.f;
}
// Dekker split: h = bf16(f) (RNE), returns exact residual f - h
static __device__ __forceinline__ float bf_split(float f, unsigned short& h) {
    h = f2bf(f);
    return f - bf2f(h);
}
// truncation pack: low short = bf16_trunc(a), high short = bf16_trunc(b)
static __device__ __forceinline__ unsigned pack_trunc(float a, float b) {
    union { float f; unsigned u; } ca, cb; ca.f = a; cb.f = b;
    return (ca.u >> 16) | (cb.u & 0xFFFF0000u);
}

// ---------------------------------------------------------------------------
// Projections.
//   Qpack[b][n][32] bf16 = [qh|ql|qh|0]   Kpack[b][n][32] bf16 = [kh|kh|kl|0]
//   vT[b][c][n] bf16 — V^T computed via MFMA: C = Wh^T(frags) @ x^T(frags)
// grid: B*128 blocks (32-token tiles), 256 threads.
// ---------------------------------------------------------------------------
__global__ __launch_bounds__(256) void proj_kernel(
    const float* __restrict__ xg,
    const float* __restrict__ Wf, const float* __restrict__ bf_,
    const float* __restrict__ Wg, const float* __restrict__ bg,
    const float* __restrict__ Wh, const float* __restrict__ bh,
    unsigned short* __restrict__ Qp, unsigned short* __restrict__ Kp,
    unsigned short* __restrict__ vTg)
{
    __shared__ float xS[32 * 68];          // x tile [token][ci]
    __shared__ float WfT[8 * 68];          // Wf^T [j][ci]
    __shared__ float WgT[8 * 68];
    __shared__ unsigned short vtS[64 * 40]; // V^T tile [cout][token], pad 40

    const int t = threadIdx.x;
    const int b = blockIdx.x >> 7;
    const int n0 = (blockIdx.x & 127) * 32;

    const float* xrow = xg + ((size_t)b * NTOK + n0) * CCH;
    for (int f = t; f < 512; f += 256) {
        int r = f >> 4, c4 = (f & 15) * 4;
        *(float4*)(xS + r * 68 + c4) = *(const float4*)(xrow + r * 64 + c4);
    }
    for (int e = t; e < 512; e += 256) {
        int ci = e >> 3, j = e & 7;
        WfT[j * 68 + ci] = Wf[e];
        WgT[j * 68 + ci] = Wg[e];
    }
    __syncthreads();

    const int w = t >> 6, lane = t & 63, ml = lane & 15, quad = lane >> 4;

    // ---- V^T via MFMA: wave w owns couts w*16..w*16+15
    {
        // A-frags: A[m=cout(ml)][k=cin] = Wh[cin][cout]
        s16x8 a0, a1;
        #pragma unroll
        for (int j = 0; j < 8; ++j) {
            a0[j] = (short)f2bf(Wh[(quad * 8 + j) * 64 + w * 16 + ml]);
            a1[j] = (short)f2bf(Wh[(32 + quad * 8 + j) * 64 + w * 16 + ml]);
        }
        #pragma unroll
        for (int nf = 0; nf < 2; ++nf) {
            int tok = nf * 16 + ml;
            // B-frags: B[k=cin][n=token(ml)] = x[token][cin]
            float4 r0 = *(const float4*)(xS + tok * 68 + quad * 8);
            float4 r1 = *(const float4*)(xS + tok * 68 + quad * 8 + 4);
            float4 r2 = *(const float4*)(xS + tok * 68 + 32 + quad * 8);
            float4 r3 = *(const float4*)(xS + tok * 68 + 32 + quad * 8 + 4);
            s16x8 b0, b1;
            b0[0] = (short)f2bf(r0.x); b0[1] = (short)f2bf(r0.y);
            b0[2] = (short)f2bf(r0.z); b0[3] = (short)f2bf(r0.w);
            b0[4] = (short)f2bf(r1.x); b0[5] = (short)f2bf(r1.y);
            b0[6] = (short)f2bf(r1.z); b0[7] = (short)f2bf(r1.w);
            b1[0] = (short)f2bf(r2.x); b1[1] = (short)f2bf(r2.y);
            b1[2] = (short)f2bf(r2.z); b1[3] = (short)f2bf(r2.w);
            b1[4] = (short)f2bf(r3.x); b1[5] = (short)f2bf(r3.y);
            b1[6] = (short)f2bf(r3.z); b1[7] = (short)f2bf(r3.w);
            f32x4 cc = __builtin_amdgcn_mfma_f32_16x16x32_bf16(a0, b0, (f32x4){0.f,0.f,0.f,0.f}, 0, 0, 0);
            cc = __builtin_amdgcn_mfma_f32_16x16x32_bf16(a1, b1, cc, 0, 0, 0);
            #pragma unroll
            for (int reg = 0; reg < 4; ++reg) {
                int cout = w * 16 + quad * 4 + reg;
                vtS[cout * 40 + nf * 16 + ml] = f2bf(cc[reg] + bh[cout]);
            }
        }
    }

    // ---- q/k: thread (r = t>>3, j = t&7): fp32 VALU + Dekker pack
    {
        int r = t >> 3, j = t & 7;
        float q = bf_[j], k = bg[j];
        for (int ci = 0; ci < 64; ci += 4) {
            float4 x4 = *(const float4*)(xS + r * 68 + ci);
            float4 wf4 = *(const float4*)(WfT + j * 68 + ci);
            float4 wg4 = *(const float4*)(WgT + j * 68 + ci);
            q += x4.x * wf4.x + x4.y * wf4.y + x4.z * wf4.z + x4.w * wf4.w;
            k += x4.x * wg4.x + x4.y * wg4.y + x4.z * wg4.z + x4.w * wg4.w;
        }
        unsigned short qh, kh;
        float qres = bf_split(q, qh);
        float kres = bf_split(k, kh);
        unsigned short ql = f2bf(qres), kl = f2bf(kres);
        size_t base = ((size_t)b * NTOK + n0 + r) * 32;
        Qp[base + j]      = qh;
        Qp[base + 8 + j]  = ql;
        Qp[base + 16 + j] = qh;
        Qp[base + 24 + j] = 0;
        Kp[base + j]      = kh;
        Kp[base + 8 + j]  = kh;
        Kp[base + 16 + j] = kl;
        Kp[base + 24 + j] = 0;
    }
    __syncthreads();

    // ---- coalesced vT store
    {
        int c_ = t >> 2, chunk = t & 3;
        uint4 v = *(const uint4*)(vtS + c_ * 40 + chunk * 8);
        *(uint4*)(vTg + ((size_t)b * CCH + c_) * NTOK + n0 + chunk * 8) = v;
    }
}

// ---------------------------------------------------------------------------
// Attention with key-split. grid = B * 64 qtiles * KSPLIT = 1024 blocks.
// Block: 64 queries x 1024 keys. Wave w computes S^T for keys w*16.. of each
// 64-key tile (4 MFMAs), exp2+trunc-pack to PS (dbuf, 1 barrier/tile), then
// all waves read shared A-frags; wave w owns channels w*16..+15 for PV.
// Partials: O bf16, l fp32 -> ws; combined in combine_kernel.
// ---------------------------------------------------------------------------
__global__ __launch_bounds__(256, 4) void attn_kernel(
    const unsigned short* __restrict__ Qp,
    const unsigned short* __restrict__ Kp,
    const unsigned short* __restrict__ vTg,
    unsigned short* __restrict__ Opart,
    float* __restrict__ lpart)
{
    __shared__ unsigned short PS[2][64 * 72];  // [query][key], stride 72

    const int t = threadIdx.x;
    const int blk = blockIdx.x;
    const int b = blk >> 8;
    const int qt = (blk >> 2) & 63;
    const int ks = blk & 3;
    const int m0 = qt * 64;
    const int kb0 = ks * KPB;
    const int w = t >> 6, lane = t & 63;
    const int ml = lane & 15, quad = lane >> 4;

    const unsigned short* qpb = Qp + (size_t)b * NTOK * 32;
    const unsigned short* kpb = Kp + (size_t)b * NTOK * 32;
    const unsigned short* vtb = vTg + (size_t)b * CCH * NTOK;

    s16x8 qf[4];
    #pragma unroll
    for (int g = 0; g < 4; ++g)
        qf[g] = *(const s16x8*)(qpb + (size_t)(m0 + g * 16 + ml) * 32 + quad * 8);

    s16x8 ones;
    #pragma unroll
    for (int i = 0; i < 8; ++i) ones[i] = (short)0x3F80;

    f32x4 o[4], l[4];
    #pragma unroll
    for (int g = 0; g < 4; ++g) { o[g] = (f32x4){0.f,0.f,0.f,0.f}; l[g] = (f32x4){0.f,0.f,0.f,0.f}; }
    const f32x4 zz = {0.f, 0.f, 0.f, 0.f};

    s16x8 kf = *(const s16x8*)(kpb + (size_t)(kb0 + w * 16 + ml) * 32 + quad * 8);

    for (int jt = 0; jt < NTILE; ++jt) {
        const int buf = jt & 1;
        const int kb = kb0 + jt * 64;

        f32x4 sg[4];
        #pragma unroll
        for (int g = 0; g < 4; ++g)
            sg[g] = __builtin_amdgcn_mfma_f32_16x16x32_bf16(kf, qf[g], zz, 0, 0, 0);

        // prefetch next K frag
        {
            int kbn = kb0 + ((jt + 1) & (NTILE - 1)) * 64;
            kf = *(const s16x8*)(kpb + (size_t)(kbn + w * 16 + ml) * 32 + quad * 8);
        }
        // current tile V frags (independent of PS)
        s16x8 vf0 = *(const s16x8*)(vtb + (size_t)(w * 16 + ml) * NTOK + kb + quad * 8);
        s16x8 vf1 = *(const s16x8*)(vtb + (size_t)(w * 16 + ml) * NTOK + kb + 32 + quad * 8);

        // p = exp2(s*log2e - 20*log2e), truncation-pack pairs -> PS
        #pragma unroll
        for (int g = 0; g < 4; ++g) {
            float p0 = exp2f(fmaf(sg[g][0], 1.442695041f, -28.85390082f));
            float p1 = exp2f(fmaf(sg[g][1], 1.442695041f, -28.85390082f));
            float p2 = exp2f(fmaf(sg[g][2], 1.442695041f, -28.85390082f));
            float p3 = exp2f(fmaf(sg[g][3], 1.442695041f, -28.85390082f));
            uint2 d = { pack_trunc(p0, p1), pack_trunc(p2, p3) };
            *(uint2*)(&PS[buf][(g * 16 + ml) * 72 + w * 16 + quad * 4]) = d;
        }
        __syncthreads();

        #pragma unroll
        for (int g = 0; g < 4; ++g) {
            s16x8 ap0 = *(const s16x8*)(&PS[buf][(g * 16 + ml) * 72 + quad * 8]);
            s16x8 ap1 = *(const s16x8*)(&PS[buf][(g * 16 + ml) * 72 + 32 + quad * 8]);
            l[g] = __builtin_amdgcn_mfma_f32_16x16x32_bf16(ap0, ones, l[g], 0, 0, 0);
            l[g] = __builtin_amdgcn_mfma_f32_16x16x32_bf16(ap1, ones, l[g], 0, 0, 0);
            o[g] = __builtin_amdgcn_mfma_f32_16x16x32_bf16(ap0, vf0, o[g], 0, 0, 0);
            o[g] = __builtin_amdgcn_mfma_f32_16x16x32_bf16(ap1, vf1, o[g], 0, 0, 0);
        }
    }

    // epilogue: partial O (bf16) and l (fp32, wave 0 lane-col 0 only)
    const size_t obase = (size_t)ks * (BATCH * NTOK * 64)
                       + (size_t)b * NTOK * 64;
    #pragma unroll
    for (int g = 0; g < 4; ++g)
        #pragma unroll
        for (int reg = 0; reg < 4; ++reg) {
            int q = m0 + g * 16 + quad * 4 + reg;
            Opart[obase + (size_t)q * 64 + w * 16 + ml] = f2bf(o[g][reg]);
        }
    if (w == 0 && ml == 0) {
        #pragma unroll
        for (int g = 0; g < 4; ++g)
            #pragma unroll
            for (int reg = 0; reg < 4; ++reg)
                lpart[ks * (BATCH * NTOK) + b * NTOK + m0 + g * 16 + quad * 4 + reg] = l[g][reg];
    }
}

// ---------------------------------------------------------------------------
// Combine: out = gamma * (sum_s O_s) / (sum_s l_s) + x.  1024 blocks x 256.
// ---------------------------------------------------------------------------
__global__ __launch_bounds__(256) void combine_kernel(
    const float* __restrict__ xg,
    const unsigned short* __restrict__ Opart,
    const float* __restrict__ lpart,
    const float* __restrict__ gammaPtr,
    float* __restrict__ out)
{
    const int i4 = blockIdx.x * 256 + threadIdx.x;
    const int base = i4 * 4;
    const int tok = base >> 6;

    float lsum = 0.f;
    #pragma unroll
    for (int s = 0; s < KSPLIT; ++s)
        lsum += lpart[s * (BATCH * NTOK) + tok];

    float o0 = 0.f, o1 = 0.f, o2 = 0.f, o3 = 0.f;
    #pragma unroll
    for (int s = 0; s < KSPLIT; ++s) {
        uint2 u = *(const uint2*)(Opart + (size_t)s * (BATCH * NTOK * 64) + base);
        o0 += bf2f((unsigned short)(u.x & 0xFFFF));
        o1 += bf2f((unsigned short)(u.x >> 16));
        o2 += bf2f((unsigned short)(u.y & 0xFFFF));
        o3 += bf2f((unsigned short)(u.y >> 16));
    }
    const float4 x4 = *(const float4*)(xg + base);
    const float gi = gammaPtr[0] / lsum;
    float4 r;
    r.x = gi * o0 + x4.x;
    r.y = gi * o1 + x4.y;
    r.z = gi * o2 + x4.z;
    r.w = gi * o3 + x4.w;
    *(float4*)(out + base) = r;
}

extern "C" void kernel_launch(void* const* d_in, const int* in_sizes, int n_in,
                              void* d_out, int out_size, void* d_ws, size_t ws_size,
                              hipStream_t stream) {
    const float* x  = (const float*)d_in[0];
    const float* Wf = (const float*)d_in[1];
    const float* bf = (const float*)d_in[2];
    const float* Wg = (const float*)d_in[3];
    const float* bg = (const float*)d_in[4];
    const float* Wh = (const float*)d_in[5];
    const float* bh = (const float*)d_in[6];
    const float* gamma = (const float*)d_in[7];
    float* out = (float*)d_out;

    // ws: Qp 1MB | Kp 1MB | vT 2MB | Opart 8MB | lpart 256KB  (12.25 MB)
    char* ws = (char*)d_ws;
    unsigned short* Qp    = (unsigned short*)ws;
    unsigned short* Kp    = (unsigned short*)(ws + (1u << 20));
    unsigned short* vTg   = (unsigned short*)(ws + (2u << 20));
    unsigned short* Opart = (unsigned short*)(ws + (4u << 20));
    float*          lpart = (float*)(ws + (12u << 20));

    proj_kernel<<<BATCH * 128, 256, 0, stream>>>(x, Wf, bf, Wg, bg, Wh, bh,
                                                 Qp, Kp, vTg);
    attn_kernel<<<BATCH * 64 * KSPLIT, 256, 0, stream>>>(Qp, Kp, vTg, Opart, lpart);
    combine_kernel<<<(BATCH * NTOK * CCH) / 1024, 256, 0, stream>>>(x, Opart, lpart, gamma, out);
}